// Round 12
// baseline (175.427 us; speedup 1.0000x reference)
//
#include <hip/hip_runtime.h>
#include <stdint.h>

#define NB 16
#define NC 128
#define NOC 128
#define NF 64
#define NT 256
#define NCTX 128
#define NTAPS 9
#define NFLAT 147456
#define TEMPR 30.0f

// LDS: X only, K-major 16B chunks (8 bf16 ic elems).
// chunk = (r*4 + kq)*SXSTRIDE + col ; col 0..129 (t = t0-1+col).
#define SXCOLS 130
#define SXSTRIDE 131
#define SX_CH (12*SXSTRIDE)   // 1572 chunks = 25152 B

typedef float f32x4 __attribute__((ext_vector_type(4)));
typedef __bf16 bf16x8 __attribute__((ext_vector_type(8)));

// ---------------- kernel 1: attention (16 x softmax over 4) ----------------
__global__ void attn_kernel(const float* __restrict__ g,
                            const float* __restrict__ dk,
                            const float* __restrict__ bias,
                            float* __restrict__ att) {
    int b = threadIdx.x;
    if (b >= NB) return;
    float r0 = bias[0], r1 = bias[1], r2 = bias[2], r3 = bias[3];
    const float* gb = g + b * NCTX;
    for (int c = 0; c < NCTX; ++c) {
        float gv = gb[c];
        r0 += gv * dk[c*4+0];
        r1 += gv * dk[c*4+1];
        r2 += gv * dk[c*4+2];
        r3 += gv * dk[c*4+3];
    }
    r0 *= (1.0f/TEMPR); r1 *= (1.0f/TEMPR); r2 *= (1.0f/TEMPR); r3 *= (1.0f/TEMPR);
    float mx = fmaxf(fmaxf(r0, r1), fmaxf(r2, r3));
    float e0 = expf(r0-mx), e1 = expf(r1-mx), e2 = expf(r2-mx), e3 = expf(r3-mx);
    float s = e0+e1+e2+e3;
    att[b*4+0] = e0/s; att[b*4+1] = e1/s; att[b*4+2] = e2/s; att[b*4+3] = e3/s;
}

// ------- kernel 2: blend 4 banks -> bf16 W K-major: [b][c4:4][tap:9][kq:4][oc:128][8]
__global__ void agg_kernel(const float* __restrict__ w,
                           const float* __restrict__ att,
                           unsigned short* __restrict__ wb) {
    int idx = blockIdx.x * 256 + threadIdx.x;   // 16*128*128 = 262144
    int ic = idx & 127;
    int oc = (idx >> 7) & 127;
    int b  = idx >> 14;
    float a0 = att[b*4+0], a1 = att[b*4+1], a2 = att[b*4+2], a3 = att[b*4+3];
    int d0 = (oc*NC + ic) * NTAPS;
    int c4 = ic >> 5;
    int kq = (ic >> 3) & 3;
    int e  = ic & 7;
    #pragma unroll
    for (int tap = 0; tap < NTAPS; ++tap) {
        float s = a0 * w[0*NFLAT + d0 + tap]
                + a1 * w[1*NFLAT + d0 + tap]
                + a2 * w[2*NFLAT + d0 + tap]
                + a3 * w[3*NFLAT + d0 + tap];
        __bf16 h = (__bf16)s;
        unsigned short u = *(unsigned short*)&h;
        int chunk = (tap * 4 + kq) * 128 + oc;                    // within c4 block
        wb[(((b * 4 + c4) * (NTAPS*4*NOC)) + chunk) * 8 + e] = u;
    }
}

// ------------------- kernel 3: MFMA implicit-GEMM conv -------------------
// R11 structure at HALF the register footprint -> 4 waves/SIMD:
//  - rocprof VGPR_Count excludes AGPR; R5-R11 all sat at VGPR+acc(64 AGPR)
//    = 150-190 unified -> 2 waves/SIMD (the 21% occupancy wall).
//  - X staged inline (no 48-reg prefetch): with 4 desynced blocks/CU the
//    OTHER blocks' MFMA hides staging latency (intra-block prefetch obsolete).
//  - A (weights) from L2 via depth-2 named ladder; taps 0/1 issued before
//    the barrier so they fly under the stage phase.
//  - __launch_bounds__(256,4): cap = 128 unified; design uses ~60 VGPR + 64 AGPR.
__global__ __launch_bounds__(256, 4) void conv_kernel(
        const float* __restrict__ x,
        const unsigned short* __restrict__ wb,
        float* __restrict__ out) {
    __shared__ __align__(16) unsigned short sx[SX_CH * 8];

    // bijective XCD swizzle: 2048 blocks -> 256 contiguous logical per XCD = 2 batches
    const int p_  = blockIdx.x;
    const int lg  = (p_ & 7) * 256 + (p_ >> 3);
    const int b   = lg >> 7;            // batch
    const int y   = (lg >> 1) & 63;     // output row
    const int t0  = (lg & 1) * 128;     // t half

    const int tid  = threadIdx.x;
    const int lane = tid & 63;
    const int wid  = tid >> 6;
    const int wpix = wid & 1;    // 64-pix half
    const int woc  = wid >> 1;   // 64-oc half
    const int l15  = lane & 15;
    const int l4   = lane >> 4;

    f32x4 acc[4][4];
    #pragma unroll
    for (int m = 0; m < 4; ++m)
        #pragma unroll
        for (int n = 0; n < 4; ++n)
            acc[m][n] = (f32x4){0.f, 0.f, 0.f, 0.f};

    const float* xb = x + (b * NC) * (NF * NT);
    // per-thread A base: chunk (l4*128 + woc*64 + l15) within a (c4,tap) slice
    const unsigned short* const wbase =
        wb + b * (NTAPS * NOC * NC) + (l4 * 128 + woc * 64 + l15) * 8;
    // per-thread B base (compute)
    const unsigned short* const sxp = sx + (l4 * SXSTRIDE + wpix * 64 + l15) * 8;

    // X staging decomposition: unit u = tid + j*256 (j<6):
    //   e=u&3 (ic pair), kq=(u>>2)&3, q=(u>>4)&31 (4-col group), r=u>>9 (row)
    const int se  = tid & 3;
    const int skq = (tid >> 2) & 3;

    bf16x8 A0[4], A1[4];

    auto loadA = [&](bf16x8* dst, int c4, int tap) {
        const unsigned short* wt = wbase + (c4 * NTAPS + tap) * 4096;
        dst[0] = *(const bf16x8*)(wt);
        dst[1] = *(const bf16x8*)(wt + 128);
        dst[2] = *(const bf16x8*)(wt + 256);
        dst[3] = *(const bf16x8*)(wt + 384);
    };

    // inline X stage: load -> cvt -> LDS write, one unit at a time (lean regs)
    auto stage_x = [&](int c4) {
        const int ic = c4 * 32 + skq * 8 + se * 2;
        #pragma unroll
        for (int j = 0; j < 6; ++j) {
            const int u = tid + j * 256;
            const int q = (u >> 4) & 31;
            const int r = u >> 9;
            const int iy = y - 1 + r;
            f32x4 v0 = (f32x4){0.f,0.f,0.f,0.f};
            f32x4 v1 = v0;
            if ((unsigned)iy < (unsigned)NF) {
                const float* src = xb + (ic * NF + iy) * NT + t0 + q * 4;
                v0 = *(const f32x4*)src;
                v1 = *(const f32x4*)(src + NF * NT);
            }
            unsigned short* dst =
                sx + ((r * 4 + skq) * SXSTRIDE + q * 4 + 1) * 8 + se * 2;
            #pragma unroll
            for (int jj = 0; jj < 4; ++jj) {
                __bf16 h0 = (__bf16)v0[jj];
                __bf16 h1 = (__bf16)v1[jj];
                unsigned pk = (unsigned)*(unsigned short*)&h0
                            | ((unsigned)*(unsigned short*)&h1 << 16);
                *(unsigned*)(dst + jj * 8) = pk;
            }
        }
        if (tid < 96) {
            const int side = (tid >> 4) & 1;
            const int r    = tid >> 5;           // 0..2
            const int t    = side ? (t0 + 128) : (t0 - 1);
            const int iy   = y - 1 + r;
            const int col  = side ? (SXCOLS - 1) : 0;
            float f0 = 0.f, f1 = 0.f;
            if ((unsigned)iy < (unsigned)NF && (unsigned)t < (unsigned)NT) {
                const float* src = xb + (ic * NF + iy) * NT + t;
                f0 = src[0];
                f1 = src[NF * NT];
            }
            __bf16 h0 = (__bf16)f0;
            __bf16 h1 = (__bf16)f1;
            unsigned pk = (unsigned)*(unsigned short*)&h0
                        | ((unsigned)*(unsigned short*)&h1 << 16);
            *(unsigned*)(sx + ((r * 4 + skq) * SXSTRIDE + col) * 8 + se * 2) = pk;
        }
    };

#define DO_TAP(KY, KX, A) do {                                                 \
        bf16x8 bfv[4];                                                         \
        _Pragma("unroll")                                                      \
        for (int n = 0; n < 4; ++n)                                            \
            bfv[n] = *(const bf16x8*)(sxp +                                    \
                        ((KY)*4*SXSTRIDE + (KX) + n*16) * 8);                  \
        _Pragma("unroll")                                                      \
        for (int m = 0; m < 4; ++m)                                            \
            _Pragma("unroll")                                                  \
            for (int n = 0; n < 4; ++n)                                        \
                acc[m][n] = __builtin_amdgcn_mfma_f32_16x16x32_bf16(           \
                    A[m], bfv[n], acc[m][n], 0, 0, 0);                         \
    } while (0)

    for (int c4 = 0; c4 < 4; ++c4) {
        // A taps 0,1 fly under the stage phase (no LDS dependency)
        loadA(A0, c4, 0);
        loadA(A1, c4, 1);
        __syncthreads();              // prev compute done reading sx
        stage_x(c4);
        __syncthreads();              // sx ready

        DO_TAP(0, 0, A0); loadA(A0, c4, 2);
        DO_TAP(0, 1, A1); loadA(A1, c4, 3);
        DO_TAP(0, 2, A0); loadA(A0, c4, 4);
        DO_TAP(1, 0, A1); loadA(A1, c4, 5);
        DO_TAP(1, 1, A0); loadA(A0, c4, 6);
        DO_TAP(1, 2, A1); loadA(A1, c4, 7);
        DO_TAP(2, 0, A0); loadA(A0, c4, 8);
        DO_TAP(2, 1, A1);
        DO_TAP(2, 2, A0);
    }
#undef DO_TAP

    // ---- epilogue: D[row=oc=(l>>4)*4+r][col=pix=l&15]
    #pragma unroll
    for (int m = 0; m < 4; ++m) {
        int ocb = woc * 64 + m * 16 + l4 * 4;
        #pragma unroll
        for (int r = 0; r < 4; ++r) {
            float* orow = out + ((b * NOC + ocb + r) * NF + y) * NT + t0;
            #pragma unroll
            for (int n = 0; n < 4; ++n)
                orow[wpix * 64 + n * 16 + l15] = acc[m][n][r];
        }
    }
}

extern "C" void kernel_launch(void* const* d_in, const int* in_sizes, int n_in,
                              void* d_out, int out_size, void* d_ws, size_t ws_size,
                              hipStream_t stream) {
    const float* x    = (const float*)d_in[0];
    const float* g    = (const float*)d_in[1];
    const float* dk   = (const float*)d_in[2];
    const float* bias = (const float*)d_in[3];
    const float* w    = (const float*)d_in[4];
    float* out = (float*)d_out;

    float* att = (float*)d_ws;                                  // 64 floats
    unsigned short* wb = (unsigned short*)((char*)d_ws + 256);  // 16*9*128*128 bf16, K-major

    attn_kernel<<<dim3(1), dim3(64), 0, stream>>>(g, dk, bias, att);
    agg_kernel<<<dim3(1024), dim3(256), 0, stream>>>(w, att, wb);
    conv_kernel<<<dim3(2048), dim3(256), 0, stream>>>(x, wb, out);
}

// Round 14
// 151.954 us; speedup vs baseline: 1.1545x; 1.1545x over previous
//
#include <hip/hip_runtime.h>
#include <stdint.h>

#define NB 16
#define NC 128
#define NOC 128
#define NF 64
#define NT 256
#define NCTX 128
#define NTAPS 9
#define NFLAT 147456
#define TEMPR 30.0f

// LDS: X only, K-major 16B chunks (8 bf16 ic elems).
// chunk = (r*4 + kq)*SXSTRIDE + col ; col = t+1: col 0 = t=-1, 1..256 = t 0..255,
// 257 = t=256 (both halos zero). Col 258 is pad (never read/written).
// Odd stride 259: X u32 stage-writes spread 2-way over 32 banks (free);
// B b128 reads: l4-groups at bank starts {0,12,24,4} -> conflict-free.
#define SXCOLS 258
#define SXSTRIDE 259
#define SX_CH (12*SXSTRIDE)   // 3108 chunks = 49728 B

typedef float f32x4 __attribute__((ext_vector_type(4)));
typedef __bf16 bf16x8 __attribute__((ext_vector_type(8)));

// ---------------- kernel 1: attention (16 x softmax over 4) ----------------
__global__ void attn_kernel(const float* __restrict__ g,
                            const float* __restrict__ dk,
                            const float* __restrict__ bias,
                            float* __restrict__ att) {
    int b = threadIdx.x;
    if (b >= NB) return;
    float r0 = bias[0], r1 = bias[1], r2 = bias[2], r3 = bias[3];
    const float* gb = g + b * NCTX;
    for (int c = 0; c < NCTX; ++c) {
        float gv = gb[c];
        r0 += gv * dk[c*4+0];
        r1 += gv * dk[c*4+1];
        r2 += gv * dk[c*4+2];
        r3 += gv * dk[c*4+3];
    }
    r0 *= (1.0f/TEMPR); r1 *= (1.0f/TEMPR); r2 *= (1.0f/TEMPR); r3 *= (1.0f/TEMPR);
    float mx = fmaxf(fmaxf(r0, r1), fmaxf(r2, r3));
    float e0 = expf(r0-mx), e1 = expf(r1-mx), e2 = expf(r2-mx), e3 = expf(r3-mx);
    float s = e0+e1+e2+e3;
    att[b*4+0] = e0/s; att[b*4+1] = e1/s; att[b*4+2] = e2/s; att[b*4+3] = e3/s;
}

// ------- kernel 2: blend 4 banks -> bf16 W K-major: [b][c4:4][tap:9][kq:4][oc:128][8]
// A lane's MFMA A-fragment (oc, k=kq*8+e) is one contiguous 16B chunk.
__global__ void agg_kernel(const float* __restrict__ w,
                           const float* __restrict__ att,
                           unsigned short* __restrict__ wb) {
    int idx = blockIdx.x * 256 + threadIdx.x;   // 16*128*128 = 262144
    int ic = idx & 127;
    int oc = (idx >> 7) & 127;
    int b  = idx >> 14;
    float a0 = att[b*4+0], a1 = att[b*4+1], a2 = att[b*4+2], a3 = att[b*4+3];
    int d0 = (oc*NC + ic) * NTAPS;
    int c4 = ic >> 5;
    int kq = (ic >> 3) & 3;
    int e  = ic & 7;
    #pragma unroll
    for (int tap = 0; tap < NTAPS; ++tap) {
        float s = a0 * w[0*NFLAT + d0 + tap]
                + a1 * w[1*NFLAT + d0 + tap]
                + a2 * w[2*NFLAT + d0 + tap]
                + a3 * w[3*NFLAT + d0 + tap];
        __bf16 h = (__bf16)s;
        unsigned short u = *(unsigned short*)&h;
        int chunk = (tap * 4 + kq) * 128 + oc;                    // within c4 block
        wb[(((b * 4 + c4) * (NTAPS*4*NOC)) + chunk) * 8 + e] = u;
    }
}

// ------------------- kernel 3: MFMA implicit-GEMM conv -------------------
// LDS-read-diet design (the binding pipe per R1-R12 accounting):
//  - wave tile 64oc x 128pix, acc[4][8] (128 AGPR): B-reads/MFMA = 0.25 (was 0.5)
//  - A (weights) NEVER touches LDS: per-(c4,ky) burst of 12 b128 from the
//    L2-resident K-major panel (48 VGPR, one latency per 96 MFMA; ky0 burst
//    hoisted above the barriers to fly under X staging)
//  - __launch_bounds__(256,2): 256-unified-reg cap; acc128 + ~100 VGPR fits.
//    (R2/R3's acc[4][8] failed via the default 128-VGPR pin + spills.)
//  - LDS = X only, 48.6KB, full 256-t row: 2 desynced 4-wave blocks/CU.
// R13 bug fixed: sxp base had a spurious +1 -> taps shifted AND read of the
// unwritten pad col 258 (NaN). col(read) must be p + KX = (base l15) + KX + n*16.
__global__ __launch_bounds__(256, 2) void conv_kernel(
        const float* __restrict__ x,
        const unsigned short* __restrict__ wb,
        float* __restrict__ out) {
    __shared__ __align__(16) unsigned short sx[SX_CH * 8];

    // bijective XCD swizzle: 1024 blocks -> 128 contiguous logical per XCD = 2 batches
    const int p_  = blockIdx.x;
    const int lg  = (p_ & 7) * 128 + (p_ >> 3);
    const int b   = lg >> 6;            // batch
    const int y   = lg & 63;            // output row

    const int tid  = threadIdx.x;
    const int lane = tid & 63;
    const int wid  = tid >> 6;          // 4 waves
    const int thalf = wid & 1;          // 128-pix t half
    const int woc   = wid >> 1;         // 64-oc half
    const int l15  = lane & 15;
    const int l4   = lane >> 4;

    f32x4 acc[4][8];
    #pragma unroll
    for (int m = 0; m < 4; ++m)
        #pragma unroll
        for (int n = 0; n < 8; ++n)
            acc[m][n] = (f32x4){0.f, 0.f, 0.f, 0.f};

    const float* xb = x + (b * NC) * (NF * NT);
    // per-thread A base: chunk (l4*128 + woc*64 + l15) within a (c4,tap) slice
    const unsigned short* const wbase =
        wb + b * (NTAPS * NOC * NC) + (l4 * 128 + woc * 64 + l15) * 8;
    // per-thread B base: chunk l4*STRIDE + pixel(thalf*128+l15); +KX+n*16 at use
    const unsigned short* const sxp =
        sx + (l4 * SXSTRIDE + thalf * 128 + l15) * 8;

    // X staging decomposition: e=tid&3 (ic pair), kq=(tid>>2)&3, qb=tid>>4 (0..15)
    const int se  = tid & 3;
    const int skq = (tid >> 2) & 3;
    const int sqb = tid >> 4;

    bf16x8 a0[4], a1[4], a2[4];   // A frags for kx=0,1,2 (literal indices only)

    auto burstA = [&](int c4, int ky) {
        const unsigned short* s0 = wbase + (c4 * 9 + ky * 3 + 0) * 4096;
        const unsigned short* s1 = s0 + 4096;
        const unsigned short* s2 = s1 + 4096;
        #pragma unroll
        for (int m = 0; m < 4; ++m) a0[m] = *(const bf16x8*)(s0 + m * 128);
        #pragma unroll
        for (int m = 0; m < 4; ++m) a1[m] = *(const bf16x8*)(s1 + m * 128);
        #pragma unroll
        for (int m = 0; m < 4; ++m) a2[m] = *(const bf16x8*)(s2 + m * 128);
    };

    auto stage_x = [&](int c4) {
        const int ic = c4 * 32 + skq * 8 + se * 2;
        #pragma unroll
        for (int j = 0; j < 12; ++j) {
            const int q  = sqb + (j & 3) * 16;     // 0..63 (4-col group)
            const int r  = j >> 2;                 // 0..2
            const int iy = y - 1 + r;
            f32x4 v0 = (f32x4){0.f,0.f,0.f,0.f};
            f32x4 v1 = v0;
            if ((unsigned)iy < (unsigned)NF) {
                const float* src = xb + (ic * NF + iy) * NT + q * 4;
                v0 = *(const f32x4*)src;
                v1 = *(const f32x4*)(src + NF * NT);
            }
            unsigned short* dst =
                sx + ((r * 4 + skq) * SXSTRIDE + q * 4 + 1) * 8 + se * 2;
            #pragma unroll
            for (int jj = 0; jj < 4; ++jj) {
                __bf16 h0 = (__bf16)v0[jj];
                __bf16 h1 = (__bf16)v1[jj];
                unsigned pk = (unsigned)*(unsigned short*)&h0
                            | ((unsigned)*(unsigned short*)&h1 << 16);
                *(unsigned*)(dst + jj * 8) = pk;
            }
        }
        // halo cols: t=-1 -> col 0, t=256 -> col 257; both always zero
        if (tid < 96) {
            const int e    = tid & 3;
            const int kq   = (tid >> 2) & 3;
            const int rr   = tid >> 4;             // 0..5
            const int r    = rr % 3;
            const int side = rr / 3;
            const int col  = side ? (SXCOLS - 1) : 0;
            *(unsigned*)(sx + ((r * 4 + kq) * SXSTRIDE + col) * 8 + e * 2) = 0u;
        }
    };

#define DO_KX(KY, KX, A) do {                                                  \
        bf16x8 bfv[8];                                                         \
        _Pragma("unroll")                                                      \
        for (int n = 0; n < 8; ++n)                                            \
            bfv[n] = *(const bf16x8*)(sxp +                                    \
                        ((KY)*4*SXSTRIDE + (KX) + n*16) * 8);                  \
        _Pragma("unroll")                                                      \
        for (int m = 0; m < 4; ++m)                                            \
            _Pragma("unroll")                                                  \
            for (int n = 0; n < 8; ++n)                                        \
                acc[m][n] = __builtin_amdgcn_mfma_f32_16x16x32_bf16(           \
                    A[m], bfv[n], acc[m][n], 0, 0, 0);                         \
    } while (0)

    for (int c4 = 0; c4 < 4; ++c4) {
        burstA(c4, 0);                // flies under the staging phase
        __syncthreads();              // prev compute done reading sx
        stage_x(c4);
        __syncthreads();              // sx ready

        DO_KX(0, 0, a0); DO_KX(0, 1, a1); DO_KX(0, 2, a2);
        burstA(c4, 1);
        DO_KX(1, 0, a0); DO_KX(1, 1, a1); DO_KX(1, 2, a2);
        burstA(c4, 2);
        DO_KX(2, 0, a0); DO_KX(2, 1, a1); DO_KX(2, 2, a2);
    }
#undef DO_KX

    // ---- epilogue: D[row=oc=(l>>4)*4+r][col=pix=l&15]
    #pragma unroll
    for (int m = 0; m < 4; ++m) {
        int ocb = woc * 64 + m * 16 + l4 * 4;
        #pragma unroll
        for (int r = 0; r < 4; ++r) {
            float* orow = out + ((b * NOC + ocb + r) * NF + y) * NT + thalf * 128;
            #pragma unroll
            for (int n = 0; n < 8; ++n)
                orow[n * 16 + l15] = acc[m][n][r];
        }
    }
}

extern "C" void kernel_launch(void* const* d_in, const int* in_sizes, int n_in,
                              void* d_out, int out_size, void* d_ws, size_t ws_size,
                              hipStream_t stream) {
    const float* x    = (const float*)d_in[0];
    const float* g    = (const float*)d_in[1];
    const float* dk   = (const float*)d_in[2];
    const float* bias = (const float*)d_in[3];
    const float* w    = (const float*)d_in[4];
    float* out = (float*)d_out;

    float* att = (float*)d_ws;                                  // 64 floats
    unsigned short* wb = (unsigned short*)((char*)d_ws + 256);  // 16*9*128*128 bf16, K-major

    attn_kernel<<<dim3(1), dim3(64), 0, stream>>>(g, dk, bias, att);
    agg_kernel<<<dim3(1024), dim3(256), 0, stream>>>(w, att, wb);
    conv_kernel<<<dim3(1024), dim3(256), 0, stream>>>(x, wb, out);
}